// Round 3
// baseline (1289.642 us; speedup 1.0000x reference)
//
#include <hip/hip_runtime.h>
#include <hip/hip_bf16.h>
#include <math.h>

#define B_  2048
#define E_  64
#define H_  512
#define T_  20
#define GK  576          // E + H
#define NG  1536         // 3*H

typedef __attribute__((ext_vector_type(8))) short short8;
typedef __attribute__((ext_vector_type(4))) float f32x4;

__device__ __forceinline__ unsigned short f2bf(float f) {
  unsigned u = __float_as_uint(f);
  u += 0x7fffu + ((u >> 16) & 1u);
  return (unsigned short)(u >> 16);
}
__device__ __forceinline__ float bf2f(unsigned short s) {
  return __uint_as_float(((unsigned)s) << 16);
}
__device__ __forceinline__ float sigmoidf_(float x) {
  return 1.0f / (1.0f + __expf(-x));
}
__device__ __forceinline__ float tanh_fast(float x) {
  float e = __expf(2.0f * x);
  return 1.0f - 2.0f / (e + 1.0f);
}

// ---------------------------------------------------------------------------
// Parallel stable counting sort. perm = stable argsort(-len), Mt[t] = #(len>t).
// Thread t owns items [t*8, t*8+8). Two-level exclusive prefix per bucket.
// ---------------------------------------------------------------------------
__global__ __launch_bounds__(256) void k_setup(const int* __restrict__ data,
                                               const int* __restrict__ st,
                                               int* __restrict__ perm,
                                               int* __restrict__ Mt) {
  __shared__ int lens[B_];
  __shared__ int hist[256][22];
  __shared__ int sub[16][22];
  __shared__ int subpre[16][22];
  __shared__ int cnt[32];
  __shared__ int offs[32];
  int tid = threadIdx.x;

  #pragma unroll
  for (int q = 0; q < 8; ++q) {
    int i = tid * 8 + q;
    lens[i] = st[data[i] * (T_ + 1) + T_];
  }
  #pragma unroll
  for (int L = 0; L < 22; ++L) hist[tid][L] = 0;
  #pragma unroll
  for (int q = 0; q < 8; ++q) hist[tid][lens[tid * 8 + q]]++;
  __syncthreads();

  // exclusive prefix within each group of 16 threads (per bucket), group sums
  for (int q = tid; q < 16 * 21; q += 256) {
    int g = q / 21, L = q % 21;
    int run = 0;
    for (int j = 0; j < 16; ++j) {
      int v = hist[g * 16 + j][L];
      hist[g * 16 + j][L] = run;
      run += v;
    }
    sub[g][L] = run;
  }
  __syncthreads();
  if (tid < 21) {
    int run = 0;
    for (int g = 0; g < 16; ++g) { subpre[g][tid] = run; run += sub[g][tid]; }
    cnt[tid] = run;
  }
  __syncthreads();
  if (tid <= 20) {
    int s = 0;
    for (int L = tid + 1; L <= 20; ++L) s += cnt[L];
    offs[tid] = s;               // #items with len > tid
  }
  __syncthreads();
  if (tid < T_) Mt[tid] = offs[tid];

  int g = tid >> 4;
  #pragma unroll
  for (int q = 0; q < 8; ++q) {
    int i = tid * 8 + q;
    int L = lens[i];
    int rk = subpre[g][L] + hist[tid][L];
    hist[tid][L] += 1;
    perm[offs[L] + rk] = i;
  }
}

__global__ void k_schars(const int* __restrict__ data, const int* __restrict__ st,
                         const int* __restrict__ perm, int* __restrict__ schars_T) {
  int idx = blockIdx.x * 256 + threadIdx.x;
  if (idx >= B_ * T_) return;
  int t = idx >> 11;
  int j = idx & (B_ - 1);
  schars_T[idx] = st[data[perm[j]] * (T_ + 1) + t];
}

__global__ void k_zero(float* __restrict__ p, int n) {
  int i = blockIdx.x * 256 + threadIdx.x;
  if (i < n) p[i] = 0.0f;
}

// W -> interleaved bf16 hi/lo fragment layout: Wq[g][kg][hi8|lo8], kg=k/8
__global__ void k_wconv(const float* __restrict__ W_ih, const float* __restrict__ W_hh,
                        short* __restrict__ Wq) {
  int idx = blockIdx.x * 256 + threadIdx.x;
  if (idx >= NG * GK) return;
  int g = idx / GK, k = idx - g * GK;
  float wv = (k < E_) ? W_ih[g * E_ + k] : W_hh[g * H_ + (k - E_)];
  unsigned short hi = f2bf(wv);
  float lo = wv - bf2f(hi);
  int kg = k >> 3, e = k & 7;
  short* row = Wq + (size_t)g * 1152 + kg * 16;
  row[e]     = (short)hi;
  row[8 + e] = (short)f2bf(lo);
}

__global__ void k_embconv(const float* __restrict__ emb, short* __restrict__ embq) {
  int idx = blockIdx.x * 256 + threadIdx.x;
  if (idx >= 128 * E_) return;
  int ch = idx >> 6, k = idx & 63;
  float v = emb[idx];
  unsigned short hi = f2bf(v);
  int kg = k >> 3, e = k & 7;
  short* row = embq + ch * 128 + kg * 16;
  row[e]     = (short)hi;
  row[8 + e] = (short)f2bf(v - bf2f(hi));
}

// ---------------------------------------------------------------------------
// One GRU step. NO LDS, NO barriers: every MFMA fragment is loaded directly
// from global in fragment layout (hi/lo pairs share a 64B line).
// Block: 512 thr = 8 waves (2 row x 4 col), tile 128 rows x 64 out-cols.
// Wave: 64 rows x 16 out-cols; acc = 4 rowfrags x {r, z, nx, nh}.
// ---------------------------------------------------------------------------
#define mf(a, b, c) __builtin_amdgcn_mfma_f32_16x16x32_bf16(a, b, c, 0, 0, 0)

#define DO_CHUNK(AP0, AP1, AP2, AP3, OFFA, OFFW, ACCN)                        \
  {                                                                           \
    short8 wh0 = *(const short8*)(w0 + (OFFW));                               \
    short8 wl0 = *(const short8*)(w0 + (OFFW) + 8);                           \
    short8 wh1 = *(const short8*)(w1 + (OFFW));                               \
    short8 wl1 = *(const short8*)(w1 + (OFFW) + 8);                           \
    short8 wh2 = *(const short8*)(w2 + (OFFW));                               \
    short8 wl2 = *(const short8*)(w2 + (OFFW) + 8);                           \
    short8 ah0 = *(const short8*)((AP0) + (OFFA));                            \
    short8 al0 = *(const short8*)((AP0) + (OFFA) + 8);                        \
    short8 ah1 = *(const short8*)((AP1) + (OFFA));                            \
    short8 al1 = *(const short8*)((AP1) + (OFFA) + 8);                        \
    short8 ah2 = *(const short8*)((AP2) + (OFFA));                            \
    short8 al2 = *(const short8*)((AP2) + (OFFA) + 8);                        \
    short8 ah3 = *(const short8*)((AP3) + (OFFA));                            \
    short8 al3 = *(const short8*)((AP3) + (OFFA) + 8);                        \
    accr[0] = mf(ah0, wh0, accr[0]); accr[0] = mf(al0, wh0, accr[0]); accr[0] = mf(ah0, wl0, accr[0]); \
    accz[0] = mf(ah0, wh1, accz[0]); accz[0] = mf(al0, wh1, accz[0]); accz[0] = mf(ah0, wl1, accz[0]); \
    ACCN[0] = mf(ah0, wh2, ACCN[0]); ACCN[0] = mf(al0, wh2, ACCN[0]); ACCN[0] = mf(ah0, wl2, ACCN[0]); \
    accr[1] = mf(ah1, wh0, accr[1]); accr[1] = mf(al1, wh0, accr[1]); accr[1] = mf(ah1, wl0, accr[1]); \
    accz[1] = mf(ah1, wh1, accz[1]); accz[1] = mf(al1, wh1, accz[1]); accz[1] = mf(ah1, wl1, accz[1]); \
    ACCN[1] = mf(ah1, wh2, ACCN[1]); ACCN[1] = mf(al1, wh2, ACCN[1]); ACCN[1] = mf(ah1, wl2, ACCN[1]); \
    accr[2] = mf(ah2, wh0, accr[2]); accr[2] = mf(al2, wh0, accr[2]); accr[2] = mf(ah2, wl0, accr[2]); \
    accz[2] = mf(ah2, wh1, accz[2]); accz[2] = mf(al2, wh1, accz[2]); accz[2] = mf(ah2, wl1, accz[2]); \
    ACCN[2] = mf(ah2, wh2, ACCN[2]); ACCN[2] = mf(al2, wh2, ACCN[2]); ACCN[2] = mf(ah2, wl2, ACCN[2]); \
    accr[3] = mf(ah3, wh0, accr[3]); accr[3] = mf(al3, wh0, accr[3]); accr[3] = mf(ah3, wl0, accr[3]); \
    accz[3] = mf(ah3, wh1, accz[3]); accz[3] = mf(al3, wh1, accz[3]); accz[3] = mf(ah3, wl1, accz[3]); \
    ACCN[3] = mf(ah3, wh2, ACCN[3]); ACCN[3] = mf(al3, wh2, ACCN[3]); ACCN[3] = mf(ah3, wl2, ACCN[3]); \
  }

__global__ __launch_bounds__(512) void k_step(
    int t, const int* __restrict__ Mt, const int* __restrict__ schars_T,
    const short* __restrict__ embq, const short* __restrict__ Wq,
    const float* __restrict__ b_ih, const float* __restrict__ b_hh,
    const short* __restrict__ rq, short* __restrict__ wq,
    float* __restrict__ hf) {
  int M = Mt[t];
  int m0 = blockIdx.x * 128;
  if (m0 >= M) return;
  int n0 = blockIdx.y * 64;

  int tid = threadIdx.x;
  int w   = tid >> 6;
  int wr  = w >> 2;
  int wc  = w & 3;
  int l   = tid & 63;
  int ln  = l & 15;
  int kg4 = l >> 4;

  int rowb = m0 + wr * 64;
  int cb   = n0 + wc * 16;

  int ch0 = schars_T[t * B_ + rowb +  0 + ln];
  int ch1 = schars_T[t * B_ + rowb + 16 + ln];
  int ch2 = schars_T[t * B_ + rowb + 32 + ln];
  int ch3 = schars_T[t * B_ + rowb + 48 + ln];

  const short* w0 = Wq + (size_t)(0 * H_ + cb + ln) * 1152;
  const short* w1 = Wq + (size_t)(1 * H_ + cb + ln) * 1152;
  const short* w2 = Wq + (size_t)(2 * H_ + cb + ln) * 1152;
  const short* a0 = rq + (size_t)(rowb +  0 + ln) * 1024;
  const short* a1 = rq + (size_t)(rowb + 16 + ln) * 1024;
  const short* a2 = rq + (size_t)(rowb + 32 + ln) * 1024;
  const short* a3 = rq + (size_t)(rowb + 48 + ln) * 1024;
  const short* e0 = embq + ch0 * 128;
  const short* e1 = embq + ch1 * 128;
  const short* e2 = embq + ch2 * 128;
  const short* e3 = embq + ch3 * 128;

  f32x4 accr[4], accz[4], accnx[4], accnh[4];
  #pragma unroll
  for (int i = 0; i < 4; ++i) {
    accr[i] = (f32x4){0.f, 0.f, 0.f, 0.f};
    accz[i] = (f32x4){0.f, 0.f, 0.f, 0.f};
    accnx[i] = (f32x4){0.f, 0.f, 0.f, 0.f};
    accnh[i] = (f32x4){0.f, 0.f, 0.f, 0.f};
  }

  // emb chunks: k = 0..64
  #pragma unroll
  for (int c = 0; c < 2; ++c) {
    int off = (c * 4 + kg4) * 16;
    DO_CHUNK(e0, e1, e2, e3, off, off, accnx);
  }
  // h chunks: k = 64..576
  #pragma unroll 2
  for (int kh = 0; kh < 16; ++kh) {
    int offa = (kh * 4 + kg4) * 16;
    int offw = ((kh + 2) * 4 + kg4) * 16;
    DO_CHUNK(a0, a1, a2, a3, offa, offw, accnh);
  }

  // epilogue
  int colg = cb + ln;
  float br  = b_ih[colg] + b_hh[colg];
  float bz  = b_ih[H_ + colg] + b_hh[H_ + colg];
  float bnx = b_ih[2 * H_ + colg];
  float bnh = b_hh[2 * H_ + colg];
  #pragma unroll
  for (int rf = 0; rf < 4; ++rf) {
    #pragma unroll
    for (int q = 0; q < 4; ++q) {
      int row = rowb + rf * 16 + kg4 * 4 + q;
      if (row < M) {
        float pr = accr[rf][q] + br;
        float pz = accz[rf][q] + bz;
        float xn = accnx[rf][q] + bnx;
        float hn = accnh[rf][q] + bnh;
        float r = sigmoidf_(pr);
        float z = sigmoidf_(pz);
        float n = tanh_fast(xn + r * hn);
        float hold = hf[row * H_ + colg];
        float hnew = (1.0f - z) * n + z * hold;
        hf[row * H_ + colg] = hnew;
        unsigned short hb = f2bf(hnew);
        unsigned short lb = f2bf(hnew - bf2f(hb));
        short* wp = wq + (size_t)row * 1024 + (colg >> 3) * 16 + (colg & 7);
        wp[0] = (short)hb;
        wp[8] = (short)lb;
      }
    }
  }
}

__global__ void k_gather(const float* __restrict__ hf, const int* __restrict__ perm,
                         float* __restrict__ out) {
  int idx = blockIdx.x * 256 + threadIdx.x;
  if (idx >= B_ * H_) return;
  int i = idx >> 9;
  int cc = idx & (H_ - 1);
  out[idx] = hf[perm[i] * H_ + cc];
}

extern "C" void kernel_launch(void* const* d_in, const int* in_sizes, int n_in,
                              void* d_out, int out_size, void* d_ws, size_t ws_size,
                              hipStream_t stream) {
  const int*   data = (const int*)d_in[0];
  const int*   st   = (const int*)d_in[1];
  const float* emb  = (const float*)d_in[2];
  const float* W_ih = (const float*)d_in[3];
  const float* W_hh = (const float*)d_in[4];
  const float* b_ih = (const float*)d_in[5];
  const float* b_hh = (const float*)d_in[6];
  float* out = (float*)d_out;

  // workspace layout (~15.8 MB)
  float* hf   = (float*)d_ws;                    // B*H fp32 (4 MB)
  short* hqA  = (short*)(hf + B_ * H_);          // B*H hi/lo interleaved (4 MB)
  short* hqB  = hqA + B_ * H_ * 2;               // 4 MB
  short* Wq   = hqB + B_ * H_ * 2;               // NG*GK*2 shorts (3.54 MB)
  short* embq = Wq + (size_t)NG * GK * 2;        // 128*64*2 shorts
  int* perm   = (int*)(embq + 128 * E_ * 2);
  int* Mt     = perm + B_;
  int* schars = Mt + 32;

  k_setup<<<1, 256, 0, stream>>>(data, st, perm, Mt);
  k_schars<<<(B_ * T_ + 255) / 256, 256, 0, stream>>>(data, st, perm, schars);
  // zero hf (1M floats) + hqA (4MB = 1M float-equivalents) in one pass
  k_zero<<<(2 * B_ * H_) / 256, 256, 0, stream>>>(hf, 2 * B_ * H_);
  k_wconv<<<(NG * GK + 255) / 256, 256, 0, stream>>>(W_ih, W_hh, Wq);
  k_embconv<<<(128 * E_ + 255) / 256, 256, 0, stream>>>(emb, embq);

  dim3 grid(B_ / 128, 8);
  for (int t = 0; t < T_; ++t) {
    const short* rq = (t & 1) ? hqB : hqA;
    short*       wqp = (t & 1) ? hqA : hqB;
    k_step<<<grid, 512, 0, stream>>>(t, Mt, schars, embq, Wq, b_ih, b_hh,
                                     rq, wqp, hf);
  }

  k_gather<<<(B_ * H_) / 256, 256, 0, stream>>>(hf, perm, out);
}

// Round 4
// 295.424 us; speedup vs baseline: 4.3654x; 4.3654x over previous
//
#include <hip/hip_runtime.h>
#include <hip/hip_bf16.h>
#include <math.h>

#define B_  2048
#define E_  64
#define H_  512
#define T_  20
#define NWP (16*18*96*32)   // Wp elements

typedef _Float16 half8 __attribute__((ext_vector_type(8)));
typedef __attribute__((ext_vector_type(4))) float f32x4;

#define mf16(a, b, c) __builtin_amdgcn_mfma_f32_16x16x32_f16(a, b, c, 0, 0, 0)

__device__ __forceinline__ float sigmoidf_(float x) {
  return 1.0f / (1.0f + __expf(-x));
}
__device__ __forceinline__ float tanh_fast(float x) {
  float e = __expf(2.0f * x);
  return 1.0f - 2.0f / (e + 1.0f);
}

// ---------------------------------------------------------------------------
// Parallel stable counting sort (validated round 3).
// ---------------------------------------------------------------------------
__global__ __launch_bounds__(256) void k_setup(const int* __restrict__ data,
                                               const int* __restrict__ st,
                                               int* __restrict__ perm,
                                               int* __restrict__ Mt) {
  __shared__ int lens[B_];
  __shared__ int hist[256][22];
  __shared__ int sub[16][22];
  __shared__ int subpre[16][22];
  __shared__ int cnt[32];
  __shared__ int offs[32];
  int tid = threadIdx.x;

  #pragma unroll
  for (int q = 0; q < 8; ++q) {
    int i = tid * 8 + q;
    lens[i] = st[data[i] * (T_ + 1) + T_];
  }
  #pragma unroll
  for (int L = 0; L < 22; ++L) hist[tid][L] = 0;
  #pragma unroll
  for (int q = 0; q < 8; ++q) hist[tid][lens[tid * 8 + q]]++;
  __syncthreads();

  for (int q = tid; q < 16 * 21; q += 256) {
    int g = q / 21, L = q % 21;
    int run = 0;
    for (int j = 0; j < 16; ++j) {
      int v = hist[g * 16 + j][L];
      hist[g * 16 + j][L] = run;
      run += v;
    }
    sub[g][L] = run;
  }
  __syncthreads();
  if (tid < 21) {
    int run = 0;
    for (int g = 0; g < 16; ++g) { subpre[g][tid] = run; run += sub[g][tid]; }
    cnt[tid] = run;
  }
  __syncthreads();
  if (tid <= 20) {
    int s = 0;
    for (int L = tid + 1; L <= 20; ++L) s += cnt[L];
    offs[tid] = s;
  }
  __syncthreads();
  if (tid < T_) Mt[tid] = offs[tid];

  int g = tid >> 4;
  #pragma unroll
  for (int q = 0; q < 8; ++q) {
    int i = tid * 8 + q;
    int L = lens[i];
    int rk = subpre[g][L] + hist[tid][L];
    hist[tid][L] += 1;
    perm[offs[L] + rk] = i;
  }
}

__global__ void k_schars(const int* __restrict__ data, const int* __restrict__ st,
                         const int* __restrict__ perm, int* __restrict__ schars_T) {
  int idx = blockIdx.x * 256 + threadIdx.x;
  if (idx >= B_ * T_) return;
  int t = idx >> 11;
  int j = idx & (B_ - 1);
  schars_T[idx] = st[data[perm[j]] * (T_ + 1) + t];
}

__global__ void k_zero(float* __restrict__ p, int n) {
  int i = blockIdx.x * 256 + threadIdx.x;
  if (i < n) p[i] = 0.0f;
}

// W -> fp16, packed per (colblock, chunk): Wp[cb][c][gc96][32] contiguous 6KB tiles.
// gc96 = gate*32 + col32; global gate-row g = gate*512 + cb*32 + col32; k = c*32+kk.
__global__ void k_wconv(const float* __restrict__ W_ih, const float* __restrict__ W_hh,
                        _Float16* __restrict__ Wp) {
  int idx = blockIdx.x * 256 + threadIdx.x;
  if (idx >= NWP) return;
  int kk = idx & 31;
  int r = idx >> 5;
  int gc = r % 96;  r /= 96;
  int c  = r % 18;  r /= 18;
  int cb = r;
  int gate = gc >> 5, col = gc & 31;
  int g = gate * H_ + cb * 32 + col;
  int k = c * 32 + kk;
  float wv = (k < E_) ? W_ih[g * E_ + k] : W_hh[g * H_ + (k - E_)];
  Wp[idx] = (_Float16)wv;
}

__global__ void k_embconv(const float* __restrict__ emb, _Float16* __restrict__ embp) {
  int idx = blockIdx.x * 256 + threadIdx.x;
  if (idx >= 128 * E_) return;
  embp[idx] = (_Float16)emb[idx];
}

// ---------------------------------------------------------------------------
// One GRU step, fp16 single-pass MFMA, dbuf LDS, 1 barrier/chunk.
// Block 256 thr = 4 waves (2 rowgroups x 2 colgroups); tile 128 rows x
// (3 gates x 32 hcols). Wave: 64 rows x 16 hcols x 3 gates.
// ---------------------------------------------------------------------------
__global__ __launch_bounds__(256) void k_step(
    int t, const int* __restrict__ Mt, const int* __restrict__ schars_T,
    const _Float16* __restrict__ embp, const _Float16* __restrict__ Wp,
    const float* __restrict__ b_ih, const float* __restrict__ b_hh,
    _Float16* __restrict__ hq, float* __restrict__ hf) {
  int M = Mt[t];
  int m0 = blockIdx.x * 128;
  if (m0 >= M) return;
  int cb = blockIdx.y;

  __shared__ __attribute__((aligned(16))) _Float16 As[2][128][40];
  __shared__ __attribute__((aligned(16))) _Float16 Ws[2][96][40];

  int tid = threadIdx.x;
  int w = tid >> 6, wr = w >> 1, wc = w & 1;
  int l = tid & 63, ln = l & 15, kc = l >> 4;

  // staging unit mapping
  int rA0 = tid >> 2,        qA0 = tid & 3;
  int rA1 = (tid + 256) >> 2, qA1 = tid & 3;
  int gW0 = tid >> 2,        kW0 = tid & 3;
  bool hasW1 = (tid < 128);
  int gW1 = (tid + 256) >> 2, kW1 = tid & 3;

  const _Float16* wbase = Wp + (size_t)cb * 18 * (96 * 32);

  half8 a0, a1, w0r, w1r;

  // ---- prologue: stage chunk 0 directly, load chunk 1 to regs ----
  {
    int ch0 = schars_T[t * B_ + m0 + rA0];
    int ch1 = schars_T[t * B_ + m0 + rA1];
    a0 = *(const half8*)(embp + ch0 * E_ + qA0 * 8);
    a1 = *(const half8*)(embp + ch1 * E_ + qA1 * 8);
    const _Float16* ws0 = wbase;
    w0r = *(const half8*)(ws0 + tid * 8);
    if (hasW1) w1r = *(const half8*)(ws0 + (tid + 256) * 8);
    *(half8*)&As[0][rA0][qA0 * 8] = a0;
    *(half8*)&As[0][rA1][qA1 * 8] = a1;
    *(half8*)&Ws[0][gW0][kW0 * 8] = w0r;
    if (hasW1) *(half8*)&Ws[0][gW1][kW1 * 8] = w1r;
    a0 = *(const half8*)(embp + ch0 * E_ + 32 + qA0 * 8);
    a1 = *(const half8*)(embp + ch1 * E_ + 32 + qA1 * 8);
    const _Float16* ws1 = wbase + 96 * 32;
    w0r = *(const half8*)(ws1 + tid * 8);
    if (hasW1) w1r = *(const half8*)(ws1 + (tid + 256) * 8);
  }
  __syncthreads();

  f32x4 accr[4], accz[4], accnx[4], accnh[4];
  #pragma unroll
  for (int i = 0; i < 4; ++i) {
    accr[i] = (f32x4){0.f, 0.f, 0.f, 0.f};
    accz[i] = (f32x4){0.f, 0.f, 0.f, 0.f};
    accnx[i] = (f32x4){0.f, 0.f, 0.f, 0.f};
    accnh[i] = (f32x4){0.f, 0.f, 0.f, 0.f};
  }

  int nch = (t == 0) ? 2 : 18;
  for (int c = 0; c < nch; ++c) {
    int b = c & 1;
    if (c + 1 < nch) {      // write held regs (chunk c+1) into other buffer
      *(half8*)&As[b ^ 1][rA0][qA0 * 8] = a0;
      *(half8*)&As[b ^ 1][rA1][qA1 * 8] = a1;
      *(half8*)&Ws[b ^ 1][gW0][kW0 * 8] = w0r;
      if (hasW1) *(half8*)&Ws[b ^ 1][gW1][kW1 * 8] = w1r;
    }
    if (c + 2 < nch) {      // prefetch chunk c+2 (always an h chunk)
      const _Float16* asrc = hq + (size_t)m0 * H_ + (c + 2 - 2) * 32;
      a0 = *(const half8*)(asrc + rA0 * H_ + qA0 * 8);
      a1 = *(const half8*)(asrc + rA1 * H_ + qA1 * 8);
      const _Float16* ws = wbase + (c + 2) * (96 * 32);
      w0r = *(const half8*)(ws + tid * 8);
      if (hasW1) w1r = *(const half8*)(ws + (tid + 256) * 8);
    }
    // ---- compute chunk c ----
    half8 af[4], wf[3];
    #pragma unroll
    for (int rf = 0; rf < 4; ++rf)
      af[rf] = *(const half8*)&As[b][wr * 64 + rf * 16 + ln][kc * 8];
    #pragma unroll
    for (int g = 0; g < 3; ++g)
      wf[g] = *(const half8*)&Ws[b][g * 32 + wc * 16 + ln][kc * 8];
    #pragma unroll
    for (int rf = 0; rf < 4; ++rf) {
      accr[rf] = mf16(af[rf], wf[0], accr[rf]);
      accz[rf] = mf16(af[rf], wf[1], accz[rf]);
    }
    if (c < 2) {
      #pragma unroll
      for (int rf = 0; rf < 4; ++rf) accnx[rf] = mf16(af[rf], wf[2], accnx[rf]);
    } else {
      #pragma unroll
      for (int rf = 0; rf < 4; ++rf) accnh[rf] = mf16(af[rf], wf[2], accnh[rf]);
    }
    __syncthreads();
  }

  // ---- epilogue: gates + state update ----
  int colg = cb * 32 + wc * 16 + ln;
  float br  = b_ih[colg] + b_hh[colg];
  float bz  = b_ih[H_ + colg] + b_hh[H_ + colg];
  float bnx = b_ih[2 * H_ + colg];
  float bnh = b_hh[2 * H_ + colg];
  #pragma unroll
  for (int rf = 0; rf < 4; ++rf) {
    #pragma unroll
    for (int q = 0; q < 4; ++q) {
      int row = m0 + wr * 64 + rf * 16 + kc * 4 + q;
      if (row < M) {
        float pr = accr[rf][q] + br;
        float pz = accz[rf][q] + bz;
        float xn = accnx[rf][q] + bnx;
        float hn = accnh[rf][q] + bnh;
        float r = sigmoidf_(pr);
        float z = sigmoidf_(pz);
        float n = tanh_fast(xn + r * hn);
        float hold = hf[row * H_ + colg];
        float hnew = (1.0f - z) * n + z * hold;
        hf[row * H_ + colg] = hnew;
        hq[row * H_ + colg] = (_Float16)hnew;
      }
    }
  }
}

__global__ void k_gather(const float* __restrict__ hf, const int* __restrict__ perm,
                         float* __restrict__ out) {
  int idx = blockIdx.x * 256 + threadIdx.x;
  if (idx >= B_ * H_) return;
  int i = idx >> 9;
  int cc = idx & (H_ - 1);
  out[idx] = hf[perm[i] * H_ + cc];
}

extern "C" void kernel_launch(void* const* d_in, const int* in_sizes, int n_in,
                              void* d_out, int out_size, void* d_ws, size_t ws_size,
                              hipStream_t stream) {
  const int*   data = (const int*)d_in[0];
  const int*   st   = (const int*)d_in[1];
  const float* emb  = (const float*)d_in[2];
  const float* W_ih = (const float*)d_in[3];
  const float* W_hh = (const float*)d_in[4];
  const float* b_ih = (const float*)d_in[5];
  const float* b_hh = (const float*)d_in[6];
  float* out = (float*)d_out;

  // workspace (~8 MB)
  float*    hf   = (float*)d_ws;                    // B*H fp32
  _Float16* hq   = (_Float16*)(hf + B_ * H_);       // B*H fp16
  _Float16* Wp   = hq + B_ * H_;                    // NWP fp16
  _Float16* embp = Wp + NWP;                        // 128*E fp16
  int* perm   = (int*)(embp + 128 * E_);
  int* Mt     = perm + B_;
  int* schars = Mt + 32;

  k_setup<<<1, 256, 0, stream>>>(data, st, perm, Mt);
  k_schars<<<(B_ * T_ + 255) / 256, 256, 0, stream>>>(data, st, perm, schars);
  // zero hf (1M floats) + hq (1M halfs = 512K floats) contiguous
  k_zero<<<(B_ * H_ + B_ * H_ / 2) / 256, 256, 0, stream>>>(hf, B_ * H_ + B_ * H_ / 2);
  k_wconv<<<(NWP + 255) / 256, 256, 0, stream>>>(W_ih, W_hh, Wp);
  k_embconv<<<(128 * E_ + 255) / 256, 256, 0, stream>>>(emb, embp);

  dim3 grid(B_ / 128, 16);
  for (int t = 0; t < T_; ++t) {
    k_step<<<grid, 256, 0, stream>>>(t, Mt, schars, embp, Wp, b_ih, b_hh, hq, hf);
  }

  k_gather<<<(B_ * H_) / 256, 256, 0, stream>>>(hf, perm, out);
}